// Round 5
// baseline (185.904 us; speedup 1.0000x reference)
//
#include <hip/hip_runtime.h>
#include <math.h>

// Attention pooling, B=32, S=4096, ENC=512.
// context[b,e] = sum_s softmax_s(enc[b,s,:]·w_enc) * enc[b,s,e]
// (hidden/w_dec/bias add a per-b constant to energies -> softmax-invariant -> dropped)
//
// Single fused kernel, last-block-done combine:
//  - one WAVE per 64-row chunk; lane l covers cols [4l,4l+4) and [256+4l,260+4l)
//    (two contiguous 1KB wave-loads per row); 64-lane butterfly for the energy dot;
//    8-row groups with ping-pong register double-buffer; online softmax per group.
//  - block writes its 4 chunk-partials, then atomicAdd on counter[b]; the last
//    block for batch b combines that batch's P partials (no 2nd kernel launch).
//  - nontemporal loads for the 256 MiB enc stream (no reuse; keep L2 for partials).

#define B_ 32
#define S_ 4096
#define ENC_ 512
#define TPB 256
#define G 8

typedef float f4 __attribute__((ext_vector_type(4)));

__device__ __forceinline__ float dot4(const f4 a, const f4 b) {
    return a.x * b.x + a.y * b.y + a.z * b.z + a.w * b.w;
}

__global__ __launch_bounds__(TPB) void attn_fused(
    const float* __restrict__ enc,   // [B, S, 512]
    const float* __restrict__ W,     // [1, 1024]; first 512 = w_enc
    float* __restrict__ pm,          // [B*P] partial max
    float* __restrict__ pl,          // [B*P] partial sum
    float* __restrict__ pc,          // [B*P, 512] partial (unnormalized) context
    int* __restrict__ counter,       // [B_] zeroed before launch
    float* __restrict__ out,         // [B, 512]
    int R, int P)                    // R = rows per wave-chunk (multiple of 16)
{
    const int b    = blockIdx.y;
    const int tid  = threadIdx.x;
    const int wave = tid >> 6;
    const int lane = tid & 63;
    const int wid  = (blockIdx.x << 2) | wave;   // chunk id in [0,P)
    const int cA0  = lane << 2;
    const int cB0  = 256 + (lane << 2);

    const f4 wA = *reinterpret_cast<const f4*>(W + cA0);
    const f4 wB = *reinterpret_cast<const f4*>(W + cB0);

    const float* row = enc + ((size_t)b * S_ + (size_t)wid * R) * ENC_;

    f4 accA = {0.f, 0.f, 0.f, 0.f}, accB = {0.f, 0.f, 0.f, 0.f};
    float m = -INFINITY, l = 0.f;

    f4 dA0[G], dB0[G], dA1[G], dB1[G];

#define LOADG(DA, DB, base_row) { \
    const float* _p = row + (size_t)(base_row) * ENC_; \
    _Pragma("unroll") \
    for (int i = 0; i < G; ++i) { \
        DA[i] = __builtin_nontemporal_load( \
                    reinterpret_cast<const f4*>(_p + (size_t)i * ENC_ + cA0)); \
        DB[i] = __builtin_nontemporal_load( \
                    reinterpret_cast<const f4*>(_p + (size_t)i * ENC_ + cB0)); \
    } }

#define PROC(DA, DB) { \
    float e[G]; \
    _Pragma("unroll") \
    for (int i = 0; i < G; ++i) e[i] = dot4(DA[i], wA) + dot4(DB[i], wB); \
    _Pragma("unroll") \
    for (int i = 0; i < G; ++i) { \
        float v = e[i]; \
        v += __shfl_xor(v, 1, 64);  v += __shfl_xor(v, 2, 64); \
        v += __shfl_xor(v, 4, 64);  v += __shfl_xor(v, 8, 64); \
        v += __shfl_xor(v, 16, 64); v += __shfl_xor(v, 32, 64); \
        e[i] = v; \
    } \
    float gm = e[0]; \
    _Pragma("unroll") \
    for (int i = 1; i < G; ++i) gm = fmaxf(gm, e[i]); \
    const float mn = fmaxf(m, gm); \
    const float sc = __expf(m - mn);  /* first group: exp(-inf)=0 */ \
    m = mn; l *= sc; \
    accA *= sc; accB *= sc; \
    _Pragma("unroll") \
    for (int i = 0; i < G; ++i) { \
        const float pw = __expf(e[i] - mn); l += pw; \
        accA += pw * DA[i]; \
        accB += pw * DB[i]; \
    } }

    LOADG(dA0, dB0, 0);
    const int ng = R / G;             // even (R multiple of 16)
    for (int g = 0; g < ng; g += 2) {
        if (g + 1 < ng) LOADG(dA1, dB1, (g + 1) * G);
        PROC(dA0, dB0);
        if (g + 2 < ng) LOADG(dA0, dB0, (g + 2) * G);
        if (g + 1 < ng) PROC(dA1, dB1);
    }

    const int idx = b * P + wid;
    *reinterpret_cast<f4*>(pc + (size_t)idx * ENC_ + cA0) = accA;
    *reinterpret_cast<f4*>(pc + (size_t)idx * ENC_ + cB0) = accB;
    if (lane == 0) { pm[idx] = m; pl[idx] = l; }

#undef LOADG
#undef PROC

    // ---- last-block-done combine for batch b ----
    __threadfence();                  // release this block's partials (device scope)
    __syncthreads();
    __shared__ int isLast;
    if (tid == 0) {
        const int v = atomicAdd(&counter[b], 1);
        isLast = (v == (P >> 2) - 1);
    }
    __syncthreads();
    if (!isLast) return;
    __threadfence();                  // acquire other blocks' partials

    // lane-parallel M and L over the P chunk-partials (P <= 64)
    const float mv = (lane < P) ? pm[b * P + lane] : -INFINITY;
    float M = mv;
#pragma unroll
    for (int o = 32; o >= 1; o >>= 1) M = fmaxf(M, __shfl_xor(M, o, 64));
    const float sv = (lane < P) ? __expf(mv - M) : 0.f;
    float L = (lane < P) ? pl[b * P + lane] * sv : 0.f;
#pragma unroll
    for (int o = 32; o >= 1; o >>= 1) L += __shfl_xor(L, o, 64);

    // each thread accumulates 2 columns across all P partials
    const int col = tid << 1;
    float ax = 0.f, ay = 0.f;
#pragma unroll 8
    for (int i = 0; i < P; ++i) {
        const float s = __shfl(sv, i & 63, 64);
        const float2 v = *reinterpret_cast<const float2*>(
            pc + ((size_t)(b * P + i) << 9) + col);
        ax += v.x * s; ay += v.y * s;
    }
    const float inv = 1.f / L;
    float2 o2; o2.x = ax * inv; o2.y = ay * inv;
    *reinterpret_cast<float2*>(out + ((size_t)b << 9) + col) = o2;
}

extern "C" void kernel_launch(void* const* d_in, const int* in_sizes, int n_in,
                              void* d_out, int out_size, void* d_ws, size_t ws_size,
                              hipStream_t stream) {
    const float* enc = (const float*)d_in[0];
    const float* W   = (const float*)d_in[2];
    float* out       = (float*)d_out;

    // P chunks per batch (P <= 64 for the lane-parallel combine); R mult of 16
    int P = 64;
    while (P > 4 && 256 + (size_t)B_ * P * (ENC_ + 2) * sizeof(float) > ws_size) P >>= 1;
    const int R = S_ / P;

    int*   counter = (int*)d_ws;                        // [B_]
    float* pm = (float*)((char*)d_ws + 256);            // [B_*P]
    float* pl = pm + (size_t)B_ * P;                    // [B_*P]
    float* pc = pl + (size_t)B_ * P;                    // [B_*P, 512]

    (void)hipMemsetAsync(counter, 0, B_ * sizeof(int), stream);

    dim3 grid(P / 4, B_);
    attn_fused<<<grid, TPB, 0, stream>>>(enc, W, pm, pl, pc, counter, out, R, P);
}

// Round 6
// 153.417 us; speedup vs baseline: 1.2118x; 1.2118x over previous
//
#include <hip/hip_runtime.h>
#include <math.h>

// Attention pooling, B=32, S=4096, ENC=512.
// context[b,e] = sum_s softmax_s(enc[b,s,:]·w_enc) * enc[b,s,e]
// (hidden/w_dec/bias add a per-b constant to energies -> softmax-invariant -> dropped)
//
// Single fused kernel, last-block-done combine:
//  - one WAVE per 64-row chunk; lane l covers cols [4l,4l+4) and [256+4l,260+4l)
//    (two contiguous 1KB wave-loads per row); 64-lane butterfly for the energy dot;
//    8-row groups with ping-pong register double-buffer; online softmax per group.
//  - block writes its 4 chunk-partials, then atomicAdd on counter[b]; the last
//    block for batch b combines that batch's P partials (no 2nd kernel launch).
//  - PLAIN vector loads. R5 lesson: __builtin_nontemporal_load made the compiler
//    sink the loads into the consume loop (VGPR 124 < the 128 needed for the
//    ping-pong buffers) -> pipeline collapsed -> latency-bound 1.5 TB/s.

#define B_ 32
#define S_ 4096
#define ENC_ 512
#define TPB 256
#define G 8

typedef float f4 __attribute__((ext_vector_type(4)));

__device__ __forceinline__ float dot4(const f4 a, const f4 b) {
    return a.x * b.x + a.y * b.y + a.z * b.z + a.w * b.w;
}

__global__ __launch_bounds__(TPB) void attn_fused(
    const float* __restrict__ enc,   // [B, S, 512]
    const float* __restrict__ W,     // [1, 1024]; first 512 = w_enc
    float* __restrict__ pm,          // [B*P] partial max
    float* __restrict__ pl,          // [B*P] partial sum
    float* __restrict__ pc,          // [B*P, 512] partial (unnormalized) context
    int* __restrict__ counter,       // [B_] zeroed before launch
    float* __restrict__ out,         // [B, 512]
    int R, int P)                    // R = rows per wave-chunk (multiple of 16)
{
    const int b    = blockIdx.y;
    const int tid  = threadIdx.x;
    const int wave = tid >> 6;
    const int lane = tid & 63;
    const int wid  = (blockIdx.x << 2) | wave;   // chunk id in [0,P)
    const int cA0  = lane << 2;
    const int cB0  = 256 + (lane << 2);

    const f4 wA = *reinterpret_cast<const f4*>(W + cA0);
    const f4 wB = *reinterpret_cast<const f4*>(W + cB0);

    const float* row = enc + ((size_t)b * S_ + (size_t)wid * R) * ENC_;

    f4 accA = {0.f, 0.f, 0.f, 0.f}, accB = {0.f, 0.f, 0.f, 0.f};
    float m = -INFINITY, l = 0.f;

    f4 dA0[G], dB0[G], dA1[G], dB1[G];

#define LOADG(DA, DB, base_row) { \
    const float* _p = row + (size_t)(base_row) * ENC_; \
    _Pragma("unroll") \
    for (int i = 0; i < G; ++i) { \
        DA[i] = *reinterpret_cast<const f4*>(_p + (size_t)i * ENC_ + cA0); \
        DB[i] = *reinterpret_cast<const f4*>(_p + (size_t)i * ENC_ + cB0); \
    } }

#define PROC(DA, DB) { \
    float e[G]; \
    _Pragma("unroll") \
    for (int i = 0; i < G; ++i) e[i] = dot4(DA[i], wA) + dot4(DB[i], wB); \
    _Pragma("unroll") \
    for (int i = 0; i < G; ++i) { \
        float v = e[i]; \
        v += __shfl_xor(v, 1, 64);  v += __shfl_xor(v, 2, 64); \
        v += __shfl_xor(v, 4, 64);  v += __shfl_xor(v, 8, 64); \
        v += __shfl_xor(v, 16, 64); v += __shfl_xor(v, 32, 64); \
        e[i] = v; \
    } \
    float gm = e[0]; \
    _Pragma("unroll") \
    for (int i = 1; i < G; ++i) gm = fmaxf(gm, e[i]); \
    const float mn = fmaxf(m, gm); \
    const float sc = __expf(m - mn);  /* first group: exp(-inf)=0 */ \
    m = mn; l *= sc; \
    accA *= sc; accB *= sc; \
    _Pragma("unroll") \
    for (int i = 0; i < G; ++i) { \
        const float pw = __expf(e[i] - mn); l += pw; \
        accA += pw * DA[i]; \
        accB += pw * DB[i]; \
    } }

    LOADG(dA0, dB0, 0);
    const int ng = R / G;             // even (R multiple of 16)
    for (int g = 0; g < ng; g += 2) {
        if (g + 1 < ng) LOADG(dA1, dB1, (g + 1) * G);
        PROC(dA0, dB0);
        if (g + 2 < ng) LOADG(dA0, dB0, (g + 2) * G);
        if (g + 1 < ng) PROC(dA1, dB1);
    }

    const int idx = b * P + wid;
    *reinterpret_cast<f4*>(pc + (size_t)idx * ENC_ + cA0) = accA;
    *reinterpret_cast<f4*>(pc + (size_t)idx * ENC_ + cB0) = accB;
    if (lane == 0) { pm[idx] = m; pl[idx] = l; }

#undef LOADG
#undef PROC

    // ---- last-block-done combine for batch b ----
    __threadfence();                  // release this block's partials (device scope)
    __syncthreads();
    __shared__ int isLast;
    if (tid == 0) {
        const int v = atomicAdd(&counter[b], 1);
        isLast = (v == (P >> 2) - 1);
    }
    __syncthreads();
    if (!isLast) return;
    __threadfence();                  // acquire other blocks' partials

    // lane-parallel M and L over the P chunk-partials (P <= 64)
    const float mv = (lane < P) ? pm[b * P + lane] : -INFINITY;
    float M = mv;
#pragma unroll
    for (int o = 32; o >= 1; o >>= 1) M = fmaxf(M, __shfl_xor(M, o, 64));
    const float sv = (lane < P) ? __expf(mv - M) : 0.f;
    float L = (lane < P) ? pl[b * P + lane] * sv : 0.f;
#pragma unroll
    for (int o = 32; o >= 1; o >>= 1) L += __shfl_xor(L, o, 64);

    // each thread accumulates 2 columns across all P partials
    const int col = tid << 1;
    float ax = 0.f, ay = 0.f;
#pragma unroll 8
    for (int i = 0; i < P; ++i) {
        const float s = __shfl(sv, i & 63, 64);
        const float2 v = *reinterpret_cast<const float2*>(
            pc + ((size_t)(b * P + i) << 9) + col);
        ax += v.x * s; ay += v.y * s;
    }
    const float inv = 1.f / L;
    float2 o2; o2.x = ax * inv; o2.y = ay * inv;
    *reinterpret_cast<float2*>(out + ((size_t)b << 9) + col) = o2;
}

extern "C" void kernel_launch(void* const* d_in, const int* in_sizes, int n_in,
                              void* d_out, int out_size, void* d_ws, size_t ws_size,
                              hipStream_t stream) {
    const float* enc = (const float*)d_in[0];
    const float* W   = (const float*)d_in[2];
    float* out       = (float*)d_out;

    // P chunks per batch (P <= 64 for the lane-parallel combine); R mult of 16
    int P = 64;
    while (P > 4 && 256 + (size_t)B_ * P * (ENC_ + 2) * sizeof(float) > ws_size) P >>= 1;
    const int R = S_ / P;

    int*   counter = (int*)d_ws;                        // [B_]
    float* pm = (float*)((char*)d_ws + 256);            // [B_*P]
    float* pl = pm + (size_t)B_ * P;                    // [B_*P]
    float* pc = pl + (size_t)B_ * P;                    // [B_*P, 512]

    (void)hipMemsetAsync(counter, 0, B_ * sizeof(int), stream);

    dim3 grid(P / 4, B_);
    attn_fused<<<grid, TPB, 0, stream>>>(enc, W, pm, pl, pc, counter, out, R, P);
}

// Round 7
// 55.997 us; speedup vs baseline: 3.3199x; 2.7397x over previous
//
#include <hip/hip_runtime.h>
#include <math.h>

// Attention pooling, B=32, S=4096, ENC=512.
// context[b,e] = sum_s softmax_s(enc[b,s,:]·w_enc) * enc[b,s,e]
// (hidden/w_dec/bias add a per-b constant to energies -> softmax-invariant -> dropped)
//
// R3 structure (proven 54.6 us). R5/R6 lessons:
//  - last-block-done fusion with __threadfence() costs ~100 us here: device-scope
//    release on non-coherent per-XCD L2 + the tail collapses the register
//    double-buffer (VGPR 124 < 128 needed) -> latency-bound. Two kernels it is.
//  - __builtin_nontemporal_load also defeats the prefetch pipeline. Plain loads.
//
// Kernel 1: one WAVE per 64-row chunk. Lane l covers cols [4l,4l+4) and
// [256+4l,260+4l) -> each row is two contiguous 1KB wave-loads. 64-lane
// butterfly for the energy dot; no LDS, no __syncthreads. 8-row groups,
// ping-pong register double-buffer; online softmax per group.
// Kernel 2: parallel combine, M/L lane-parallel, P split across 4 waves.

#define B_ 32
#define S_ 4096
#define ENC_ 512
#define TPB 256
#define G 8

__device__ __forceinline__ float dot4(const float4 a, const float4 b) {
    return a.x * b.x + a.y * b.y + a.z * b.z + a.w * b.w;
}

__global__ __launch_bounds__(TPB) void attn_partial(
    const float* __restrict__ enc,   // [B, S, 512]
    const float* __restrict__ W,     // [1, 1024]; first 512 = w_enc
    float* __restrict__ pm,          // [B*P] partial max
    float* __restrict__ pl,          // [B*P] partial sum
    float* __restrict__ pc,          // [B*P, 512] partial (unnormalized) context
    int R, int P)                    // R = rows per wave-chunk (multiple of 16)
{
    const int b    = blockIdx.y;
    const int wid  = (blockIdx.x << 2) | (threadIdx.x >> 6);  // chunk id in [0,P)
    const int lane = threadIdx.x & 63;
    const int cA0  = lane << 2;            // cols 4l..4l+3
    const int cB0  = 256 + (lane << 2);    // cols 256+4l..259+4l

    const float4 wA = *reinterpret_cast<const float4*>(W + cA0);
    const float4 wB = *reinterpret_cast<const float4*>(W + cB0);

    const float* row = enc + ((size_t)b * S_ + (size_t)wid * R) * ENC_;

    float4 accA = {0.f, 0.f, 0.f, 0.f}, accB = {0.f, 0.f, 0.f, 0.f};
    float m = -INFINITY, l = 0.f;

    float4 dA0[G], dB0[G], dA1[G], dB1[G];

#define LOADG(DA, DB, base_row) { \
    const float* _p = row + (size_t)(base_row) * ENC_; \
    _Pragma("unroll") \
    for (int i = 0; i < G; ++i) { \
        DA[i] = *reinterpret_cast<const float4*>(_p + (size_t)i * ENC_ + cA0); \
        DB[i] = *reinterpret_cast<const float4*>(_p + (size_t)i * ENC_ + cB0); \
    } }

#define PROC(DA, DB) { \
    float e[G]; \
    _Pragma("unroll") \
    for (int i = 0; i < G; ++i) e[i] = dot4(DA[i], wA) + dot4(DB[i], wB); \
    _Pragma("unroll") \
    for (int i = 0; i < G; ++i) { \
        float v = e[i]; \
        v += __shfl_xor(v, 1, 64);  v += __shfl_xor(v, 2, 64); \
        v += __shfl_xor(v, 4, 64);  v += __shfl_xor(v, 8, 64); \
        v += __shfl_xor(v, 16, 64); v += __shfl_xor(v, 32, 64); \
        e[i] = v; \
    } \
    float gm = e[0]; \
    _Pragma("unroll") \
    for (int i = 1; i < G; ++i) gm = fmaxf(gm, e[i]); \
    const float mn = fmaxf(m, gm); \
    const float sc = __expf(m - mn);  /* first group: exp(-inf)=0 */ \
    m = mn; l *= sc; \
    accA.x *= sc; accA.y *= sc; accA.z *= sc; accA.w *= sc; \
    accB.x *= sc; accB.y *= sc; accB.z *= sc; accB.w *= sc; \
    _Pragma("unroll") \
    for (int i = 0; i < G; ++i) { \
        const float pw = __expf(e[i] - mn); l += pw; \
        accA.x += pw * DA[i].x; accA.y += pw * DA[i].y; \
        accA.z += pw * DA[i].z; accA.w += pw * DA[i].w; \
        accB.x += pw * DB[i].x; accB.y += pw * DB[i].y; \
        accB.z += pw * DB[i].z; accB.w += pw * DB[i].w; \
    } }

    LOADG(dA0, dB0, 0);
    const int ng = R / G;             // even (R multiple of 16)
    for (int g = 0; g < ng; g += 2) {
        if (g + 1 < ng) LOADG(dA1, dB1, (g + 1) * G);
        PROC(dA0, dB0);
        if (g + 2 < ng) LOADG(dA0, dB0, (g + 2) * G);
        if (g + 1 < ng) PROC(dA1, dB1);
    }

    const int idx = b * P + wid;
    *reinterpret_cast<float4*>(pc + (size_t)idx * ENC_ + cA0) = accA;
    *reinterpret_cast<float4*>(pc + (size_t)idx * ENC_ + cB0) = accB;
    if (lane == 0) { pm[idx] = m; pl[idx] = l; }

#undef LOADG
#undef PROC
}

// grid (ENC/64, B); 256 threads. Block owns 64 cols; 4 waves split the P
// partials; M and L are computed lane-parallel (P <= 64).
__global__ __launch_bounds__(TPB) void attn_combine(
    const float* __restrict__ pm, const float* __restrict__ pl,
    const float* __restrict__ pc, float* __restrict__ out, int P)
{
    const int b    = blockIdx.y;
    const int lane = threadIdx.x & 63;
    const int wave = threadIdx.x >> 6;
    const int col  = (blockIdx.x << 6) | lane;

    // lane-parallel global max / denom over the P chunk-partials
    const float mv = (lane < P) ? pm[b * P + lane] : -INFINITY;
    float M = mv;
#pragma unroll
    for (int o = 32; o >= 1; o >>= 1) M = fmaxf(M, __shfl_xor(M, o, 64));
    const float sv = (lane < P) ? __expf(mv - M) : 0.f;   // scale for chunk `lane`
    float L = (lane < P) ? pl[b * P + lane] * sv : 0.f;
#pragma unroll
    for (int o = 32; o >= 1; o >>= 1) L += __shfl_xor(L, o, 64);

    const int per = P >> 2;                 // chunks per wave
    float acc = 0.f;
    for (int k = 0; k < per; ++k) {
        const int i = wave * per + k;
        const float s = __shfl(sv, i, 64);
        acc += pc[((size_t)(b * P + i) << 9) | col] * s;
    }

    __shared__ float red[3][64];
    if (wave) red[wave - 1][lane] = acc;
    __syncthreads();
    if (wave == 0) {
        acc += red[0][lane] + red[1][lane] + red[2][lane];
        out[(b << 9) | col] = acc / L;
    }
}

extern "C" void kernel_launch(void* const* d_in, const int* in_sizes, int n_in,
                              void* d_out, int out_size, void* d_ws, size_t ws_size,
                              hipStream_t stream) {
    const float* enc = (const float*)d_in[0];
    const float* W   = (const float*)d_in[2];
    float* out       = (float*)d_out;

    // P chunks per batch (P<=64 so the combine's lane-parallel pass works);
    // shrink if workspace is tiny. R = S/P rows per wave, multiple of 16.
    int P = 64;
    while (P > 4 && (size_t)B_ * P * (ENC_ + 2) * sizeof(float) > ws_size) P >>= 1;
    const int R = S_ / P;

    float* pm = (float*)d_ws;
    float* pl = pm + (size_t)B_ * P;
    float* pc = pl + (size_t)B_ * P;

    dim3 grid1(P / 4, B_);
    attn_partial<<<grid1, TPB, 0, stream>>>(enc, W, pm, pl, pc, R, P);
    dim3 grid2(ENC_ / 64, B_);
    attn_combine<<<grid2, TPB, 0, stream>>>(pm, pl, pc, out, P);
}